// Round 2
// baseline (601.885 us; speedup 1.0000x reference)
//
#include <hip/hip_runtime.h>
#include <hip/hip_bf16.h>

typedef _Float16 half8 __attribute__((ext_vector_type(8)));
typedef float f32x4 __attribute__((ext_vector_type(4)));

#define NN 50000
#define NE 800000
#define TE 64

// ---------------------------------------------------------------------------
// Repack W3 [64][256] (k, 4f+l) -> fragment-ordered f16 W3re for MFMA B-frags.
// Layout: w3p[((ks*4+nt)*64 + lane)*8 + u] = W3re[j][f]
//   where j = 32*ks + 8*(lane>>4) + u  (j = 4*kk + l, kk = h2 channel, l = sh idx)
//         f = 16*nt + (lane&15)
//   and W3re[j][f] = W3[j>>2][4*f + (j&3)]
// ---------------------------------------------------------------------------
__global__ void pack_w3_kernel(const float* __restrict__ W3, _Float16* __restrict__ w3p) {
  int t = blockIdx.x * blockDim.x + threadIdx.x;
  if (t >= 8 * 4 * 64) return;
  int lane = t & 63;
  int nt   = (t >> 6) & 3;
  int ks   = t >> 8;
  int f    = 16 * nt + (lane & 15);
  int jbase = 32 * ks + 8 * (lane >> 4);
#pragma unroll
  for (int u = 0; u < 8; ++u) {
    int j = jbase + u;
    w3p[t * 8 + u] = (_Float16)W3[(j >> 2) * 256 + 4 * f + (j & 3)];
  }
}

// ---------------------------------------------------------------------------
// Y[row, lane] = scale * sum_k X[row, k] * W[k, lane]   (64x64 weight)
// One wave per row; X row reads are wave-uniform (scalar path), W coalesced.
// ---------------------------------------------------------------------------
__global__ __launch_bounds__(256)
void linear64_kernel(const float* __restrict__ X, const float* __restrict__ W,
                     float* __restrict__ Y, float scale, int nrows) {
  int gid  = blockIdx.x * 256 + (int)threadIdx.x;
  int row  = gid >> 6;
  int lane = threadIdx.x & 63;
  if (row >= nrows) return;
  const float* xr = X + (long)row * 64;
  float acc = 0.f;
#pragma unroll
  for (int k = 0; k < 64; ++k) acc = fmaf(xr[k], W[k * 64 + lane], acc);
  Y[(long)row * 64 + lane] = acc * scale;
}

__device__ __forceinline__ float swishf(float v) {
  return v / (1.f + __expf(-v));
}

// ---------------------------------------------------------------------------
// Fused edge kernel: 64 edges per block (4 waves of 64).
//  h1 = swish(r @ W1); h2 = swish(h1 @ W2)          (fp32 VALU)
//  msg = (A' @ W3re) * x_s,  A'[e,4k+l] = h2[e,k]*ef[e,l]   (f16 MFMA, K=256)
//  atomicAdd into agg[recv]
// ---------------------------------------------------------------------------
__global__ __launch_bounds__(256, 2)
void edge_kernel(const float* __restrict__ xup, const float* __restrict__ ef,
                 const float* __restrict__ rad, const int* __restrict__ senders,
                 const int* __restrict__ receivers, const int* __restrict__ mask,
                 const float* __restrict__ W1, const float* __restrict__ W2,
                 const _Float16* __restrict__ w3p, float* __restrict__ agg) {
  __shared__ float s_r[TE][9];     // +1 pad: conflict-free stride-9
  __shared__ float s_ef[TE][4];
  __shared__ float s_xs[TE][65];   // x[senders] * mask
  __shared__ float s_h1[TE][65];
  __shared__ float s_h2[TE][65];
  __shared__ int   s_recv[TE];

  const int t  = threadIdx.x;
  const long e0 = (long)blockIdx.x * TE;

  // ---- stage radial / edge-attrs / receivers ----
  for (int i = t; i < TE * 8; i += 256) s_r[i >> 3][i & 7] = rad[e0 * 8 + i];
  for (int i = t; i < TE * 4; i += 256) s_ef[i >> 2][i & 3] = ef[e0 * 4 + i];
  if (t < TE) s_recv[t] = receivers[e0 + t];

  // ---- gather x[senders] * mask -> s_xs (4 threads per edge row) ----
  {
    const int e  = t >> 2;
    const int c0 = (t & 3) * 16;
    const int sn = senders[e0 + e];
    const float m = mask[e0 + e] ? 1.0f : 0.0f;   // int32 bool
    const float4* src = reinterpret_cast<const float4*>(xup + (long)sn * 64 + c0);
#pragma unroll
    for (int q = 0; q < 4; ++q) {
      float4 v = src[q];
      s_xs[e][c0 + 4 * q + 0] = v.x * m;
      s_xs[e][c0 + 4 * q + 1] = v.y * m;
      s_xs[e][c0 + 4 * q + 2] = v.z * m;
      s_xs[e][c0 + 4 * q + 3] = v.w * m;
    }
  }
  __syncthreads();

  // ---- h1 = swish(r @ W1): thread -> (e = t&63, 16 channels) ----
  {
    const int e  = t & 63;
    const int c0 = (t >> 6) * 16;   // wave-uniform -> scalar W1 loads
    float rv[8];
#pragma unroll
    for (int k = 0; k < 8; ++k) rv[k] = s_r[e][k];
#pragma unroll
    for (int cc = 0; cc < 16; ++cc) {
      float acc = 0.f;
#pragma unroll
      for (int k = 0; k < 8; ++k) acc = fmaf(rv[k], W1[k * 64 + c0 + cc], acc);
      s_h1[e][c0 + cc] = swishf(acc);
    }
  }
  __syncthreads();

  // ---- h2 = swish(h1 @ W2) ----
  {
    const int e  = t & 63;
    const int c0 = (t >> 6) * 16;   // wave-uniform -> scalar W2 loads
    float acc[16];
#pragma unroll
    for (int cc = 0; cc < 16; ++cc) acc[cc] = 0.f;
    for (int k = 0; k < 64; ++k) {
      const float h = s_h1[e][k];   // stride-65 LDS: conflict-free
      const float4* w2r = reinterpret_cast<const float4*>(W2 + k * 64 + c0);
#pragma unroll
      for (int q = 0; q < 4; ++q) {
        float4 wv = w2r[q];
        acc[4 * q + 0] = fmaf(h, wv.x, acc[4 * q + 0]);
        acc[4 * q + 1] = fmaf(h, wv.y, acc[4 * q + 1]);
        acc[4 * q + 2] = fmaf(h, wv.z, acc[4 * q + 2]);
        acc[4 * q + 3] = fmaf(h, wv.w, acc[4 * q + 3]);
      }
    }
#pragma unroll
    for (int cc = 0; cc < 16; ++cc) s_h2[e][c0 + cc] = swishf(acc[cc]);
  }
  __syncthreads();

  // ---- stage 3: msg = (A' @ W3re) * x_s via f16 MFMA 16x16x32, K=256 ----
  {
    const int w    = t >> 6;        // wave = 16-edge M-tile
    const int lane = t & 63;
    const int m    = lane & 15;     // A row within tile
    const int g    = lane >> 4;     // k-group
    const int e_m  = w * 16 + m;

    float ef4[4];
#pragma unroll
    for (int l = 0; l < 4; ++l) ef4[l] = s_ef[e_m][l];

    f32x4 acc[4];
#pragma unroll
    for (int nt = 0; nt < 4; ++nt) acc[nt] = (f32x4){0.f, 0.f, 0.f, 0.f};

#pragma unroll
    for (int ks = 0; ks < 8; ++ks) {
      const int kk0 = 8 * ks + 2 * g;       // h2 channel pair for this lane
      const float h0  = s_h2[e_m][kk0];
      const float h1v = s_h2[e_m][kk0 + 1];
      half8 a;
#pragma unroll
      for (int l = 0; l < 4; ++l) {
        a[l]     = (_Float16)(h0 * ef4[l]);
        a[4 + l] = (_Float16)(h1v * ef4[l]);
      }
#pragma unroll
      for (int nt = 0; nt < 4; ++nt) {
        half8 b = *reinterpret_cast<const half8*>(w3p + ((size_t)(ks * 4 + nt) * 64 + lane) * 8);
        acc[nt] = __builtin_amdgcn_mfma_f32_16x16x32_f16(a, b, acc[nt], 0, 0, 0);
      }
    }

    // epilogue: C[row, col] -> msg, scale by x_s (mask folded), scatter
    const int col = lane & 15;
    const int rg  = lane >> 4;
#pragma unroll
    for (int nt = 0; nt < 4; ++nt) {
      const int f = nt * 16 + col;
#pragma unroll
      for (int i = 0; i < 4; ++i) {
        const int e_row = w * 16 + rg * 4 + i;
        const float v = acc[nt][i] * s_xs[e_row][f];
        unsafeAtomicAdd(&agg[(size_t)s_recv[e_row] * 64 + f], v);
      }
    }
  }
}

extern "C" void kernel_launch(void* const* d_in, const int* in_sizes, int n_in,
                              void* d_out, int out_size, void* d_ws, size_t ws_size,
                              hipStream_t stream) {
  const float*  nf    = (const float*)d_in[0];
  const float*  ef    = (const float*)d_in[1];
  const float*  rad   = (const float*)d_in[2];
  const int*    snd   = (const int*)d_in[3];
  const int*    rcv   = (const int*)d_in[4];
  const int*    msk   = (const int*)d_in[5];
  const float*  W_up  = (const float*)d_in[6];
  const float*  W1    = (const float*)d_in[7];
  const float*  W2    = (const float*)d_in[8];
  const float*  W3    = (const float*)d_in[9];
  const float*  W_dn  = (const float*)d_in[10];
  float* out = (float*)d_out;

  // workspace layout
  float* agg  = (float*)d_ws;                       // 50000*64 f32 = 12.8 MB
  float* xbuf = agg + (size_t)NN * 64;              // 50000*64 f32 = 12.8 MB
  _Float16* w3p = (_Float16*)(xbuf + (size_t)NN * 64); // 16384 f16 = 32 KB

  hipMemsetAsync(agg, 0, (size_t)NN * 64 * sizeof(float), stream);

  pack_w3_kernel<<<8, 256, 0, stream>>>(W3, w3p);

  // x = nf @ W_up
  linear64_kernel<<<(NN * 64) / 256, 256, 0, stream>>>(nf, W_up, xbuf, 1.0f, NN);

  // fused edge MLP + tensor product + scatter
  edge_kernel<<<NE / TE, 256, 0, stream>>>(xbuf, ef, rad, snd, rcv, msk,
                                           W1, W2, w3p, agg);

  // out = (agg / 16) @ W_down
  linear64_kernel<<<(NN * 64) / 256, 256, 0, stream>>>(agg, W_dn, out, 1.0f / 16.0f, NN);
}